// Round 1
// baseline (1123.383 us; speedup 1.0000x reference)
//
#include <hip/hip_runtime.h>
#include <math.h>

#define THR 256

// ---------------- CSR build ----------------

// Detect whether edge_index buffer is int64 (high words all zero) or int32.
// flag stays 0 -> int64; flag set to 1 -> int32.
__global__ void k_detect(const int* __restrict__ w, int* __restrict__ flag) {
  int i = blockIdx.x * blockDim.x + threadIdx.x;
  if (i < 4096) {
    if (w[2 * i + 1] != 0) atomicOr(flag, 1);
  }
}

__device__ __forceinline__ int load_idx(const int* __restrict__ w, int pos, int is32) {
  // pos indexes the logical int array of length 2E
  return is32 ? w[pos] : w[2 * pos];
}

__global__ void k_count(const int* __restrict__ ei, const int* __restrict__ flag,
                        int* __restrict__ cnt, int E) {
  int e = blockIdx.x * blockDim.x + threadIdx.x;
  if (e < E) {
    int is32 = *flag;
    int d = load_idx(ei, E + e, is32);
    atomicAdd(&cnt[d], 1);
  }
}

__global__ __launch_bounds__(1024) void k_scan(int* __restrict__ cnt_cur, int* __restrict__ off, int n) {
  __shared__ int part[1024];
  int tid = threadIdx.x;
  int chunk = (n + 1023) / 1024;
  int s0 = tid * chunk;
  int s1 = min(s0 + chunk, n);
  int s = 0;
  for (int i = s0; i < s1; ++i) s += cnt_cur[i];
  part[tid] = s;
  __syncthreads();
  for (int d = 1; d < 1024; d <<= 1) {
    int v = (tid >= d) ? part[tid - d] : 0;
    __syncthreads();
    part[tid] += v;
    __syncthreads();
  }
  int excl = (tid == 0) ? 0 : part[tid - 1];
  for (int i = s0; i < s1; ++i) {
    int c = cnt_cur[i];
    off[i] = excl;
    cnt_cur[i] = excl;   // cursor copy for scatter
    excl += c;
  }
  if (tid == 1023) off[n] = part[1023];
}

__global__ void k_scatter(const int* __restrict__ ei, const int* __restrict__ flag,
                          int* __restrict__ cur, int* __restrict__ seid,
                          int* __restrict__ ssrc, int E) {
  int e = blockIdx.x * blockDim.x + threadIdx.x;
  if (e < E) {
    int is32 = *flag;
    int d = load_idx(ei, E + e, is32);
    int s = load_idx(ei, e, is32);
    int p = atomicAdd(&cur[d], 1);
    seid[p] = e;
    ssrc[p] = s;
  }
}

// ---------------- weight prep ----------------

// WeT rows: layer0 d=0..63 ; layer1 rows 64..127 ; layer2 rows 128..383
// WeT[row*16 + k] = We[k][col]
__global__ void k_transpose_we(const float* __restrict__ We0, const float* __restrict__ We1,
                               const float* __restrict__ We2, float* __restrict__ WeT) {
  int i = blockIdx.x * blockDim.x + threadIdx.x;
  if (i >= 384 * 16) return;
  int row = i >> 4, k = i & 15;
  float v;
  if (row < 64)        v = We0[k * 64 + row];
  else if (row < 128)  v = We1[k * 64 + (row - 64)];
  else                 v = We2[k * 256 + (row - 128)];
  WeT[i] = v;
}

// waj[k*H+h] = sum_d W[k, h*64+d] * a_j[h,d] ; wai similar with a_i
__global__ void k_fold_att(const float* __restrict__ W, const float* __restrict__ att,
                           float* __restrict__ waj, float* __restrict__ wai,
                           int Cin, int H) {
  int i = blockIdx.x * blockDim.x + threadIdx.x;
  if (i >= Cin * H) return;
  int k = i / H, h = i % H;
  float sj = 0.f, si = 0.f;
  for (int d = 0; d < 64; ++d) {
    float w = W[k * (H * 64) + h * 64 + d];
    sj = fmaf(w, att[h * 192 + d], sj);
    si = fmaf(w, att[h * 192 + 64 + d], si);
  }
  waj[k * H + h] = sj;
  wai[k * H + h] = si;
}

// ajd[n*H+h] = x[n,:] . waj[:,h]
template <int CIN, int H>
__global__ void k_node_dots(const float* __restrict__ xin, const float* __restrict__ waj,
                            const float* __restrict__ wai, float* __restrict__ ajd,
                            float* __restrict__ aid, int N) {
  int n = blockIdx.x * blockDim.x + threadIdx.x;
  if (n >= N) return;
  float sj[H], si[H];
#pragma unroll
  for (int h = 0; h < H; ++h) { sj[h] = 0.f; si[h] = 0.f; }
  const float* xr = xin + (size_t)n * CIN;
#pragma unroll 4
  for (int k = 0; k < CIN; ++k) {
    float xv = xr[k];
#pragma unroll
    for (int h = 0; h < H; ++h) {
      sj[h] = fmaf(xv, waj[k * H + h], sj[h]);
      si[h] = fmaf(xv, wai[k * H + h], si[h]);
    }
  }
#pragma unroll
  for (int h = 0; h < H; ++h) {
    ajd[(size_t)n * H + h] = sj[h];
    aid[(size_t)n * H + h] = si[h];
  }
}

// ---------------- edge scalar ep ----------------

__device__ __forceinline__ float dot16(const float* __restrict__ w, const float ar[16]) {
  float p = 0.f;
#pragma unroll
  for (int k = 0; k < 16; ++k) p = fmaf(ar[k], w[k], p);
  return p;
}

// ep[e,h] = sum_d relu(ea[e]·We[:,d]) * a_p[h,d]  for all 3 layers fused
__global__ void k_ep(const float* __restrict__ ea, const float* __restrict__ WeT,
                     const float* __restrict__ att0, const float* __restrict__ att1,
                     const float* __restrict__ att2,
                     float* __restrict__ ep0, float* __restrict__ ep1,
                     float* __restrict__ ep2, int E) {
  int e = blockIdx.x * blockDim.x + threadIdx.x;
  if (e >= E) return;
  const float4* eav = reinterpret_cast<const float4*>(ea + (size_t)e * 16);
  float4 A = eav[0], B = eav[1], C = eav[2], D = eav[3];
  float ar[16] = {A.x, A.y, A.z, A.w, B.x, B.y, B.z, B.w,
                  C.x, C.y, C.z, C.w, D.x, D.y, D.z, D.w};
  float s0 = 0.f, s1 = 0.f;
  for (int d = 0; d < 64; ++d) {
    float p0 = dot16(WeT + d * 16, ar);
    float p1 = dot16(WeT + (64 + d) * 16, ar);
    s0 = fmaf(fmaxf(p0, 0.f), att0[128 + d], s0);
    s1 = fmaf(fmaxf(p1, 0.f), att1[128 + d], s1);
  }
  ep0[e] = s0;
  ep1[e] = s1;
#pragma unroll
  for (int h = 0; h < 4; ++h) {
    float s2 = 0.f;
    for (int d = 0; d < 64; ++d) {
      float p = dot16(WeT + (128 + h * 64 + d) * 16, ar);
      s2 = fmaf(fmaxf(p, 0.f), att2[h * 192 + 128 + d], s2);
    }
    ep2[(size_t)e * 4 + h] = s2;
  }
}

// ---------------- attention softmax + aggregate (in input space) ----------------

// one wave per (node, head); aggregates agg[n, h*F + :] = sum_e alpha_e * hin[src_e, :]
template <int F, int H>
__global__ __launch_bounds__(256) void k_agg(const int* __restrict__ off, const int* __restrict__ seid,
                      const int* __restrict__ ssrc, const float* __restrict__ hin,
                      const float* __restrict__ ajd, const float* __restrict__ aid,
                      const float* __restrict__ ep, float* __restrict__ outbuf, int N) {
  int wave = threadIdx.x >> 6;
  int lane = threadIdx.x & 63;
  for (int task = blockIdx.x * 4 + wave; task < N * H; task += gridDim.x * 4) {
    int n = task / H;
    int h = task % H;
    int o0 = off[n];
    int deg = off[n + 1] - o0;
    float aidn = aid[(size_t)n * H + h];

    // pass 1: online softmax (max + sum), lane-parallel over edges
    float m = -1e30f, s = 0.f;
    for (int i = lane; i < deg; i += 64) {
      int eid = seid[o0 + i];
      int sr = ssrc[o0 + i];
      float sc = ajd[(size_t)sr * H + h] + aidn + ep[(size_t)eid * H + h];
      sc = sc > 0.f ? sc : 0.2f * sc;
      float mn = fmaxf(m, sc);
      s = s * __expf(m - mn) + __expf(sc - mn);
      m = mn;
    }
#pragma unroll
    for (int o = 32; o > 0; o >>= 1) {
      float m2 = __shfl_xor(m, o, 64);
      float s2 = __shfl_xor(s, o, 64);
      float mn = fmaxf(m, m2);
      s = s * __expf(m - mn) + s2 * __expf(m2 - mn);
      m = mn;
    }
    float inv = 1.f / (s + 1e-16f);

    // pass 2: weighted feature accumulation, lane = feature
    constexpr int FPL = F / 64;
    float acc[FPL];
#pragma unroll
    for (int c = 0; c < FPL; ++c) acc[c] = 0.f;
    for (int j = 0; j < deg; ++j) {
      int eid = seid[o0 + j];
      int sr = ssrc[o0 + j];
      float sc = ajd[(size_t)sr * H + h] + aidn + ep[(size_t)eid * H + h];
      sc = sc > 0.f ? sc : 0.2f * sc;
      float al = __expf(sc - m) * inv;
      const float* hr = hin + (size_t)sr * F;
#pragma unroll
      for (int c = 0; c < FPL; ++c) acc[c] = fmaf(al, hr[c * 64 + lane], acc[c]);
    }
    float* ob = outbuf + (size_t)n * (H * F) + (size_t)h * F;
#pragma unroll
    for (int c = 0; c < FPL; ++c) ob[c * 64 + lane] = acc[c];
  }
}

// ---------------- post GEMM: out[n, h*64+j] = agg[n,h,:] @ W[:, h*64+j] (+ELU) ----------------

template <int F, int H, bool ELU_ACT>
__global__ __launch_bounds__(256) void k_post(const float* __restrict__ agg, const float* __restrict__ W,
                       float* __restrict__ out, int N) {
  constexpr int CO = H * 64;
  __shared__ float Wl[F * CO];
  for (int i = threadIdx.x; i < F * CO; i += 256) Wl[i] = W[i];
  __syncthreads();
  constexpr int GPB = 256 / CO;
  int g = threadIdx.x / CO;
  int j = threadIdx.x % CO;
  int h = j >> 6;
  for (int n = blockIdx.x * GPB + g; n < N; n += gridDim.x * GPB) {
    const float* ag = agg + (size_t)n * (H * F) + (size_t)h * F;
    float a = 0.f;
#pragma unroll 8
    for (int k = 0; k < F; ++k) a = fmaf(ag[k], Wl[k * CO + j], a);
    if (ELU_ACT) a = (a > 0.f) ? a : expm1f(a);
    out[(size_t)n * CO + j] = a;
  }
}

// ---------------- launch ----------------

extern "C" void kernel_launch(void* const* d_in, const int* in_sizes, int n_in,
                              void* d_out, int out_size, void* d_ws, size_t ws_size,
                              hipStream_t stream) {
  const float* x    = (const float*)d_in[0];
  const int*   ei   = (const int*)d_in[1];
  const float* ea   = (const float*)d_in[2];
  const float* W0   = (const float*)d_in[3];
  const float* We0  = (const float*)d_in[4];
  const float* att0 = (const float*)d_in[5];
  const float* W1   = (const float*)d_in[6];
  const float* We1  = (const float*)d_in[7];
  const float* att1 = (const float*)d_in[8];
  const float* W2   = (const float*)d_in[9];
  const float* We2  = (const float*)d_in[10];
  const float* att2 = (const float*)d_in[11];
  float* out = (float*)d_out;

  const int N = in_sizes[0] / 128;   // 50000
  const int E = in_sizes[2] / 16;    // 800000

  char* p = (char*)d_ws;
  auto alloc = [&](size_t bytes) {
    char* r = p;
    p += (bytes + 255) & ~(size_t)255;
    return r;
  };
  int*   flag = (int*)  alloc(sizeof(int));
  int*   off  = (int*)  alloc((size_t)(N + 1) * sizeof(int));
  int*   cur  = (int*)  alloc((size_t)N * sizeof(int));
  int*   seid = (int*)  alloc((size_t)E * sizeof(int));
  int*   ssrc = (int*)  alloc((size_t)E * sizeof(int));
  float* WeT  = (float*)alloc(384 * 16 * sizeof(float));
  float* waj0 = (float*)alloc(128 * sizeof(float));
  float* wai0 = (float*)alloc(128 * sizeof(float));
  float* waj1 = (float*)alloc(64 * sizeof(float));
  float* wai1 = (float*)alloc(64 * sizeof(float));
  float* waj2 = (float*)alloc(256 * sizeof(float));
  float* wai2 = (float*)alloc(256 * sizeof(float));
  float* ajd  = (float*)alloc((size_t)N * 4 * sizeof(float));
  float* aid  = (float*)alloc((size_t)N * 4 * sizeof(float));
  float* ep0  = (float*)alloc((size_t)E * sizeof(float));
  float* ep1  = (float*)alloc((size_t)E * sizeof(float));
  float* ep2  = (float*)alloc((size_t)E * 4 * sizeof(float));
  float* hbuf = (float*)alloc((size_t)N * 64 * sizeof(float));
  float* agg  = (float*)alloc((size_t)N * 256 * sizeof(float));

  const int eb = (E + THR - 1) / THR;
  const int nb = (N + THR - 1) / THR;

  hipMemsetAsync(flag, 0, sizeof(int), stream);
  hipMemsetAsync(cur, 0, (size_t)N * sizeof(int), stream);

  k_detect<<<16, THR, 0, stream>>>(ei, flag);
  k_count<<<eb, THR, 0, stream>>>(ei, flag, cur, E);
  k_scan<<<1, 1024, 0, stream>>>(cur, off, N);
  k_scatter<<<eb, THR, 0, stream>>>(ei, flag, cur, seid, ssrc, E);

  k_transpose_we<<<24, THR, 0, stream>>>(We0, We1, We2, WeT);
  k_fold_att<<<1, 128, 0, stream>>>(W0, att0, waj0, wai0, 128, 1);
  k_fold_att<<<1, 64, 0, stream>>>(W1, att1, waj1, wai1, 64, 1);
  k_fold_att<<<1, 256, 0, stream>>>(W2, att2, waj2, wai2, 64, 4);
  k_ep<<<eb, THR, 0, stream>>>(ea, WeT, att0, att1, att2, ep0, ep1, ep2, E);

  // layer 0: Cin=128, H=1
  k_node_dots<128, 1><<<nb, THR, 0, stream>>>(x, waj0, wai0, ajd, aid, N);
  k_agg<128, 1><<<(N + 3) / 4, THR, 0, stream>>>(off, seid, ssrc, x, ajd, aid, ep0, agg, N);
  k_post<128, 1, true><<<1024, THR, 0, stream>>>(agg, W0, hbuf, N);

  // layer 1: Cin=64, H=1
  k_node_dots<64, 1><<<nb, THR, 0, stream>>>(hbuf, waj1, wai1, ajd, aid, N);
  k_agg<64, 1><<<(N + 3) / 4, THR, 0, stream>>>(off, seid, ssrc, hbuf, ajd, aid, ep1, agg, N);
  k_post<64, 1, true><<<1024, THR, 0, stream>>>(agg, W1, hbuf, N);

  // layer 2: Cin=64, H=4
  k_node_dots<64, 4><<<nb, THR, 0, stream>>>(hbuf, waj2, wai2, ajd, aid, N);
  k_agg<64, 4><<<N, THR, 0, stream>>>(off, seid, ssrc, hbuf, ajd, aid, ep2, agg, N);
  k_post<64, 4, false><<<1024, THR, 0, stream>>>(agg, W2, out, N);
}

// Round 2
// 807.011 us; speedup vs baseline: 1.3920x; 1.3920x over previous
//
#include <hip/hip_runtime.h>
#include <math.h>

#define THR 256

// ---------------- CSR build ----------------

// Detect whether edge_index buffer is int64 (high words all zero) or int32.
__global__ void k_detect(const int* __restrict__ w, int* __restrict__ flag) {
  int i = blockIdx.x * blockDim.x + threadIdx.x;
  if (i < 4096) {
    if (w[2 * i + 1] != 0) atomicOr(flag, 1);
  }
}

__device__ __forceinline__ int load_idx(const int* __restrict__ w, int pos, int is32) {
  return is32 ? w[pos] : w[2 * pos];
}

__global__ void k_count(const int* __restrict__ ei, const int* __restrict__ flag,
                        int* __restrict__ cnt, int E) {
  int e = blockIdx.x * blockDim.x + threadIdx.x;
  if (e < E) {
    int is32 = *flag;
    int d = load_idx(ei, E + e, is32);
    atomicAdd(&cnt[d], 1);
  }
}

__global__ __launch_bounds__(1024) void k_scan(int* __restrict__ cnt_cur, int* __restrict__ off, int n) {
  __shared__ int part[1024];
  int tid = threadIdx.x;
  int chunk = (n + 1023) / 1024;
  int s0 = tid * chunk;
  int s1 = min(s0 + chunk, n);
  int s = 0;
  for (int i = s0; i < s1; ++i) s += cnt_cur[i];
  part[tid] = s;
  __syncthreads();
  for (int d = 1; d < 1024; d <<= 1) {
    int v = (tid >= d) ? part[tid - d] : 0;
    __syncthreads();
    part[tid] += v;
    __syncthreads();
  }
  int excl = (tid == 0) ? 0 : part[tid - 1];
  for (int i = s0; i < s1; ++i) {
    int c = cnt_cur[i];
    off[i] = excl;
    cnt_cur[i] = excl;   // cursor copy for scatter
    excl += c;
  }
  if (tid == 1023) off[n] = part[1023];
}

__global__ void k_scatter(const int* __restrict__ ei, const int* __restrict__ flag,
                          int* __restrict__ cur, int* __restrict__ pos,
                          int* __restrict__ ssrc, int E) {
  int e = blockIdx.x * blockDim.x + threadIdx.x;
  if (e < E) {
    int is32 = *flag;
    int d = load_idx(ei, E + e, is32);
    int s = load_idx(ei, e, is32);
    int p = atomicAdd(&cur[d], 1);
    pos[e] = p;
    ssrc[p] = s;
  }
}

// ---------------- weight prep ----------------

// WeT rows: layer0 d=0..63 ; layer1 rows 64..127 ; layer2 rows 128..383
__global__ void k_transpose_we(const float* __restrict__ We0, const float* __restrict__ We1,
                               const float* __restrict__ We2, float* __restrict__ WeT) {
  int i = blockIdx.x * blockDim.x + threadIdx.x;
  if (i >= 384 * 16) return;
  int row = i >> 4, k = i & 15;
  float v;
  if (row < 64)        v = We0[k * 64 + row];
  else if (row < 128)  v = We1[k * 64 + (row - 64)];
  else                 v = We2[k * 256 + (row - 128)];
  WeT[i] = v;
}

__global__ void k_fold_att(const float* __restrict__ W, const float* __restrict__ att,
                           float* __restrict__ waj, float* __restrict__ wai,
                           int Cin, int H) {
  int i = blockIdx.x * blockDim.x + threadIdx.x;
  if (i >= Cin * H) return;
  int k = i / H, h = i % H;
  float sj = 0.f, si = 0.f;
  for (int d = 0; d < 64; ++d) {
    float w = W[k * (H * 64) + h * 64 + d];
    sj = fmaf(w, att[h * 192 + d], sj);
    si = fmaf(w, att[h * 192 + 64 + d], si);
  }
  waj[k * H + h] = sj;
  wai[k * H + h] = si;
}

template <int CIN, int H>
__global__ void k_node_dots(const float* __restrict__ xin, const float* __restrict__ waj,
                            const float* __restrict__ wai, float* __restrict__ ajd,
                            float* __restrict__ aid, int N) {
  int n = blockIdx.x * blockDim.x + threadIdx.x;
  if (n >= N) return;
  float sj[H], si[H];
#pragma unroll
  for (int h = 0; h < H; ++h) { sj[h] = 0.f; si[h] = 0.f; }
  const float* xr = xin + (size_t)n * CIN;
#pragma unroll 4
  for (int k = 0; k < CIN; ++k) {
    float xv = xr[k];
#pragma unroll
    for (int h = 0; h < H; ++h) {
      sj[h] = fmaf(xv, waj[k * H + h], sj[h]);
      si[h] = fmaf(xv, wai[k * H + h], si[h]);
    }
  }
#pragma unroll
  for (int h = 0; h < H; ++h) {
    ajd[(size_t)n * H + h] = sj[h];
    aid[(size_t)n * H + h] = si[h];
  }
}

// ---------------- edge scalar ep (written directly in CSR-sorted order) ----------------

__device__ __forceinline__ float dot16(const float* __restrict__ w, const float ar[16]) {
  float p = 0.f;
#pragma unroll
  for (int k = 0; k < 16; ++k) p = fmaf(ar[k], w[k], p);
  return p;
}

__global__ void k_ep(const float* __restrict__ ea, const float* __restrict__ WeT,
                     const float* __restrict__ att0, const float* __restrict__ att1,
                     const float* __restrict__ att2, const int* __restrict__ pos,
                     float* __restrict__ ep0, float* __restrict__ ep1,
                     float* __restrict__ ep2, int E) {
  int e = blockIdx.x * blockDim.x + threadIdx.x;
  if (e >= E) return;
  const float4* eav = reinterpret_cast<const float4*>(ea + (size_t)e * 16);
  float4 A = eav[0], B = eav[1], C = eav[2], D = eav[3];
  float ar[16] = {A.x, A.y, A.z, A.w, B.x, B.y, B.z, B.w,
                  C.x, C.y, C.z, C.w, D.x, D.y, D.z, D.w};
  int p = pos[e];
  float s0 = 0.f, s1 = 0.f;
  for (int d = 0; d < 64; ++d) {
    float p0 = dot16(WeT + d * 16, ar);
    float p1 = dot16(WeT + (64 + d) * 16, ar);
    s0 = fmaf(fmaxf(p0, 0.f), att0[128 + d], s0);
    s1 = fmaf(fmaxf(p1, 0.f), att1[128 + d], s1);
  }
  ep0[p] = s0;
  ep1[p] = s1;
  float4 s2v;
  float* s2 = (float*)&s2v;
#pragma unroll
  for (int h = 0; h < 4; ++h) {
    float s = 0.f;
    for (int d = 0; d < 64; ++d) {
      float pr = dot16(WeT + (128 + h * 64 + d) * 16, ar);
      s = fmaf(fmaxf(pr, 0.f), att2[h * 192 + 128 + d], s);
    }
    s2[h] = s;
  }
  reinterpret_cast<float4*>(ep2)[p] = s2v;
}

// ---------------- fused attention softmax + aggregate ----------------

template <int H>
__device__ __forceinline__ void loadH(const float* __restrict__ p, float* v) {
  if constexpr (H == 4) {
    float4 t = *reinterpret_cast<const float4*>(p);
    v[0] = t.x; v[1] = t.y; v[2] = t.z; v[3] = t.w;
  } else {
    v[0] = *p;
  }
}

// one wave per node, all H heads together.
// agg[n, h*F + f] = sum_e alpha_{e,h} * hin[src_e, f]
template <int F, int H>
__global__ __launch_bounds__(256) void k_attn_agg(
    const int* __restrict__ off, const int* __restrict__ ssrc,
    const float* __restrict__ hin, const float* __restrict__ ajd,
    const float* __restrict__ aid, const float* __restrict__ ep,
    float* __restrict__ outbuf, int N) {
  constexpr int FPL = F / 64;
  __shared__ float ls_alpha[4][64 * H];
  __shared__ int ls_src[4][64];
  const int wave = threadIdx.x >> 6, lane = threadIdx.x & 63;
  float* const la = ls_alpha[wave];
  int* const lsrc = ls_src[wave];

  for (int n = blockIdx.x * 4 + wave; n < N; n += gridDim.x * 4) {
    const int o0 = off[n];
    const int deg = off[n + 1] - o0;
    float aidn[H];
    loadH<H>(aid + (size_t)n * H, aidn);

    // ---- pass 1: online softmax stats (lane-parallel over edges) ----
    float m[H], s[H];
#pragma unroll
    for (int h = 0; h < H; ++h) { m[h] = -1e30f; s[h] = 0.f; }
    for (int i = lane; i < deg; i += 64) {
      int sr = ssrc[o0 + i];
      float aj[H], pv[H];
      loadH<H>(ajd + (size_t)sr * H, aj);
      loadH<H>(ep + (size_t)(o0 + i) * H, pv);
#pragma unroll
      for (int h = 0; h < H; ++h) {
        float sc = aj[h] + aidn[h] + pv[h];
        sc = sc > 0.f ? sc : 0.2f * sc;
        float mn = fmaxf(m[h], sc);
        s[h] = s[h] * __expf(m[h] - mn) + __expf(sc - mn);
        m[h] = mn;
      }
    }
#pragma unroll
    for (int o = 32; o > 0; o >>= 1) {
#pragma unroll
      for (int h = 0; h < H; ++h) {
        float m2 = __shfl_xor(m[h], o, 64);
        float s2 = __shfl_xor(s[h], o, 64);
        float mn = fmaxf(m[h], m2);
        s[h] = s[h] * __expf(m[h] - mn) + s2 * __expf(m2 - mn);
        m[h] = mn;
      }
    }
    float inv[H];
#pragma unroll
    for (int h = 0; h < H; ++h) inv[h] = 1.f / (s[h] + 1e-16f);

    // ---- pass 2: chunked alpha -> LDS, then 4-way unrolled gather+FMA ----
    float acc[H][FPL];
#pragma unroll
    for (int h = 0; h < H; ++h)
#pragma unroll
      for (int c = 0; c < FPL; ++c) acc[h][c] = 0.f;

    for (int base = 0; base < deg; base += 64) {
      const int cnt = min(64, deg - base);
      if (lane < cnt) {
        int i = base + lane;
        int sr = ssrc[o0 + i];
        lsrc[lane] = sr;
        float aj[H], pv[H];
        loadH<H>(ajd + (size_t)sr * H, aj);
        loadH<H>(ep + (size_t)(o0 + i) * H, pv);
#pragma unroll
        for (int h = 0; h < H; ++h) {
          float sc = aj[h] + aidn[h] + pv[h];
          sc = sc > 0.f ? sc : 0.2f * sc;
          la[lane * H + h] = __expf(sc - m[h]) * inv[h];
        }
      }
      asm volatile("s_waitcnt lgkmcnt(0)" ::: "memory");

      int j = 0;
      for (; j + 4 <= cnt; j += 4) {
        int srj[4];
        float av[4][H];
#pragma unroll
        for (int u = 0; u < 4; ++u) {
          srj[u] = lsrc[j + u];
          loadH<H>(la + (j + u) * H, av[u]);
        }
        float v[4][FPL];
#pragma unroll
        for (int u = 0; u < 4; ++u) {
          const float* hr = hin + (size_t)srj[u] * F + lane;
#pragma unroll
          for (int c = 0; c < FPL; ++c) v[u][c] = hr[c * 64];
        }
#pragma unroll
        for (int u = 0; u < 4; ++u)
#pragma unroll
          for (int h = 0; h < H; ++h)
#pragma unroll
            for (int c = 0; c < FPL; ++c)
              acc[h][c] = fmaf(av[u][h], v[u][c], acc[h][c]);
      }
      for (; j < cnt; ++j) {
        int sr = lsrc[j];
        float av[H];
        loadH<H>(la + j * H, av);
        const float* hr = hin + (size_t)sr * F + lane;
#pragma unroll
        for (int h = 0; h < H; ++h)
#pragma unroll
          for (int c = 0; c < FPL; ++c)
            acc[h][c] = fmaf(av[h], hr[c * 64], acc[h][c]);
      }
    }

    float* ob = outbuf + (size_t)n * (H * F);
#pragma unroll
    for (int h = 0; h < H; ++h)
#pragma unroll
      for (int c = 0; c < FPL; ++c) ob[h * F + c * 64 + lane] = acc[h][c];
  }
}

// ---------------- post GEMM: out[n, h*64+j] = agg[n,h,:] @ W[:, h*64+j] (+ELU) ----------------

template <int F, int H, bool ELU_ACT>
__global__ __launch_bounds__(256) void k_post(const float* __restrict__ agg, const float* __restrict__ W,
                       float* __restrict__ out, int N) {
  constexpr int CO = H * 64;
  __shared__ float Wl[F * CO];
  for (int i = threadIdx.x; i < F * CO; i += 256) Wl[i] = W[i];
  __syncthreads();
  constexpr int GPB = 256 / CO;
  int g = threadIdx.x / CO;
  int j = threadIdx.x % CO;
  int h = j >> 6;
  for (int n = blockIdx.x * GPB + g; n < N; n += gridDim.x * GPB) {
    const float* ag = agg + (size_t)n * (H * F) + (size_t)h * F;
    float a = 0.f;
#pragma unroll 8
    for (int k = 0; k < F; ++k) a = fmaf(ag[k], Wl[k * CO + j], a);
    if (ELU_ACT) a = (a > 0.f) ? a : expm1f(a);
    out[(size_t)n * CO + j] = a;
  }
}

// ---------------- launch ----------------

extern "C" void kernel_launch(void* const* d_in, const int* in_sizes, int n_in,
                              void* d_out, int out_size, void* d_ws, size_t ws_size,
                              hipStream_t stream) {
  const float* x    = (const float*)d_in[0];
  const int*   ei   = (const int*)d_in[1];
  const float* ea   = (const float*)d_in[2];
  const float* W0   = (const float*)d_in[3];
  const float* We0  = (const float*)d_in[4];
  const float* att0 = (const float*)d_in[5];
  const float* W1   = (const float*)d_in[6];
  const float* We1  = (const float*)d_in[7];
  const float* att1 = (const float*)d_in[8];
  const float* W2   = (const float*)d_in[9];
  const float* We2  = (const float*)d_in[10];
  const float* att2 = (const float*)d_in[11];
  float* out = (float*)d_out;

  const int N = in_sizes[0] / 128;   // 50000
  const int E = in_sizes[2] / 16;    // 800000

  char* p = (char*)d_ws;
  auto alloc = [&](size_t bytes) {
    char* r = p;
    p += (bytes + 255) & ~(size_t)255;
    return r;
  };
  int*   flag = (int*)  alloc(sizeof(int));
  int*   off  = (int*)  alloc((size_t)(N + 1) * sizeof(int));
  int*   cur  = (int*)  alloc((size_t)N * sizeof(int));
  int*   pos  = (int*)  alloc((size_t)E * sizeof(int));
  int*   ssrc = (int*)  alloc((size_t)E * sizeof(int));
  float* WeT  = (float*)alloc(384 * 16 * sizeof(float));
  float* waj0 = (float*)alloc(128 * sizeof(float));
  float* wai0 = (float*)alloc(128 * sizeof(float));
  float* waj1 = (float*)alloc(64 * sizeof(float));
  float* wai1 = (float*)alloc(64 * sizeof(float));
  float* waj2 = (float*)alloc(256 * sizeof(float));
  float* wai2 = (float*)alloc(256 * sizeof(float));
  float* ajd  = (float*)alloc((size_t)N * 4 * sizeof(float));
  float* aid  = (float*)alloc((size_t)N * 4 * sizeof(float));
  float* ep0  = (float*)alloc((size_t)E * sizeof(float));
  float* ep1  = (float*)alloc((size_t)E * sizeof(float));
  float* ep2  = (float*)alloc((size_t)E * 4 * sizeof(float));
  float* hbuf = (float*)alloc((size_t)N * 64 * sizeof(float));
  float* agg  = (float*)alloc((size_t)N * 256 * sizeof(float));

  const int eb = (E + THR - 1) / THR;
  const int nb = (N + THR - 1) / THR;
  const int ab = (N + 3) / 4;

  hipMemsetAsync(flag, 0, sizeof(int), stream);
  hipMemsetAsync(cur, 0, (size_t)N * sizeof(int), stream);

  k_detect<<<16, THR, 0, stream>>>(ei, flag);
  k_count<<<eb, THR, 0, stream>>>(ei, flag, cur, E);
  k_scan<<<1, 1024, 0, stream>>>(cur, off, N);
  k_scatter<<<eb, THR, 0, stream>>>(ei, flag, cur, pos, ssrc, E);

  k_transpose_we<<<24, THR, 0, stream>>>(We0, We1, We2, WeT);
  k_fold_att<<<1, 128, 0, stream>>>(W0, att0, waj0, wai0, 128, 1);
  k_fold_att<<<1, 64, 0, stream>>>(W1, att1, waj1, wai1, 64, 1);
  k_fold_att<<<1, 256, 0, stream>>>(W2, att2, waj2, wai2, 64, 4);
  k_ep<<<eb, THR, 0, stream>>>(ea, WeT, att0, att1, att2, pos, ep0, ep1, ep2, E);

  // layer 0: Cin=128, H=1
  k_node_dots<128, 1><<<nb, THR, 0, stream>>>(x, waj0, wai0, ajd, aid, N);
  k_attn_agg<128, 1><<<ab, THR, 0, stream>>>(off, ssrc, x, ajd, aid, ep0, agg, N);
  k_post<128, 1, true><<<1024, THR, 0, stream>>>(agg, W0, hbuf, N);

  // layer 1: Cin=64, H=1
  k_node_dots<64, 1><<<nb, THR, 0, stream>>>(hbuf, waj1, wai1, ajd, aid, N);
  k_attn_agg<64, 1><<<ab, THR, 0, stream>>>(off, ssrc, hbuf, ajd, aid, ep1, agg, N);
  k_post<64, 1, true><<<1024, THR, 0, stream>>>(agg, W1, hbuf, N);

  // layer 2: Cin=64, H=4 (all heads in one wave)
  k_node_dots<64, 4><<<nb, THR, 0, stream>>>(hbuf, waj2, wai2, ajd, aid, N);
  k_attn_agg<64, 4><<<ab, THR, 0, stream>>>(off, ssrc, hbuf, ajd, aid, ep2, agg, N);
  k_post<64, 4, false><<<1024, THR, 0, stream>>>(agg, W2, out, N);
}

// Round 3
// 805.543 us; speedup vs baseline: 1.3946x; 1.0018x over previous
//
#include <hip/hip_runtime.h>
#include <math.h>

#define THR 256

// ---------------- CSR build ----------------

// Detect whether edge_index buffer is int64 (high words all zero) or int32.
__global__ void k_detect(const int* __restrict__ w, int* __restrict__ flag) {
  int i = blockIdx.x * blockDim.x + threadIdx.x;
  if (i < 4096) {
    if (w[2 * i + 1] != 0) atomicOr(flag, 1);
  }
}

__device__ __forceinline__ int load_idx(const int* __restrict__ w, int pos, int is32) {
  return is32 ? w[pos] : w[2 * pos];
}

__global__ void k_count(const int* __restrict__ ei, const int* __restrict__ flag,
                        int* __restrict__ cnt, int E) {
  int e = blockIdx.x * blockDim.x + threadIdx.x;
  if (e < E) {
    int is32 = *flag;
    int d = load_idx(ei, E + e, is32);
    atomicAdd(&cnt[d], 1);
  }
}

__global__ __launch_bounds__(1024) void k_scan(int* __restrict__ cnt_cur, int* __restrict__ off, int n) {
  __shared__ int part[1024];
  int tid = threadIdx.x;
  int chunk = (n + 1023) / 1024;
  int s0 = tid * chunk;
  int s1 = min(s0 + chunk, n);
  int s = 0;
  for (int i = s0; i < s1; ++i) s += cnt_cur[i];
  part[tid] = s;
  __syncthreads();
  for (int d = 1; d < 1024; d <<= 1) {
    int v = (tid >= d) ? part[tid - d] : 0;
    __syncthreads();
    part[tid] += v;
    __syncthreads();
  }
  int excl = (tid == 0) ? 0 : part[tid - 1];
  for (int i = s0; i < s1; ++i) {
    int c = cnt_cur[i];
    off[i] = excl;
    cnt_cur[i] = excl;   // cursor copy for scatter
    excl += c;
  }
  if (tid == 1023) off[n] = part[1023];
}

__global__ void k_scatter(const int* __restrict__ ei, const int* __restrict__ flag,
                          int* __restrict__ cur, int* __restrict__ pos,
                          int* __restrict__ ssrc, int E) {
  int e = blockIdx.x * blockDim.x + threadIdx.x;
  if (e < E) {
    int is32 = *flag;
    int d = load_idx(ei, E + e, is32);
    int s = load_idx(ei, e, is32);
    int p = atomicAdd(&cur[d], 1);
    pos[e] = p;
    ssrc[p] = s;
  }
}

// ---------------- weight prep ----------------

// WeT rows: layer0 d=0..63 ; layer1 rows 64..127 ; layer2 rows 128..383
__global__ void k_transpose_we(const float* __restrict__ We0, const float* __restrict__ We1,
                               const float* __restrict__ We2, float* __restrict__ WeT) {
  int i = blockIdx.x * blockDim.x + threadIdx.x;
  if (i >= 384 * 16) return;
  int row = i >> 4, k = i & 15;
  float v;
  if (row < 64)        v = We0[k * 64 + row];
  else if (row < 128)  v = We1[k * 64 + (row - 64)];
  else                 v = We2[k * 256 + (row - 128)];
  WeT[i] = v;
}

__global__ void k_fold_att(const float* __restrict__ W, const float* __restrict__ att,
                           float* __restrict__ waj, float* __restrict__ wai,
                           int Cin, int H) {
  int i = blockIdx.x * blockDim.x + threadIdx.x;
  if (i >= Cin * H) return;
  int k = i / H, h = i % H;
  float sj = 0.f, si = 0.f;
  for (int d = 0; d < 64; ++d) {
    float w = W[k * (H * 64) + h * 64 + d];
    sj = fmaf(w, att[h * 192 + d], sj);
    si = fmaf(w, att[h * 192 + 64 + d], si);
  }
  waj[k * H + h] = sj;
  wai[k * H + h] = si;
}

template <int CIN, int H>
__global__ void k_node_dots(const float* __restrict__ xin, const float* __restrict__ waj,
                            const float* __restrict__ wai, float* __restrict__ ajd,
                            float* __restrict__ aid, int N) {
  int n = blockIdx.x * blockDim.x + threadIdx.x;
  if (n >= N) return;
  float sj[H], si[H];
#pragma unroll
  for (int h = 0; h < H; ++h) { sj[h] = 0.f; si[h] = 0.f; }
  const float* xr = xin + (size_t)n * CIN;
#pragma unroll 4
  for (int k = 0; k < CIN; ++k) {
    float xv = xr[k];
#pragma unroll
    for (int h = 0; h < H; ++h) {
      sj[h] = fmaf(xv, waj[k * H + h], sj[h]);
      si[h] = fmaf(xv, wai[k * H + h], si[h]);
    }
  }
#pragma unroll
  for (int h = 0; h < H; ++h) {
    ajd[(size_t)n * H + h] = sj[h];
    aid[(size_t)n * H + h] = si[h];
  }
}

// ---------------- edge scalar ep (written directly in CSR-sorted order) ----------------

__device__ __forceinline__ float dot16(const float* __restrict__ w, const float ar[16]) {
  float p = 0.f;
#pragma unroll
  for (int k = 0; k < 16; ++k) p = fmaf(ar[k], w[k], p);
  return p;
}

__global__ void k_ep(const float* __restrict__ ea, const float* __restrict__ WeT,
                     const float* __restrict__ att0, const float* __restrict__ att1,
                     const float* __restrict__ att2, const int* __restrict__ pos,
                     float* __restrict__ ep0, float* __restrict__ ep1,
                     float* __restrict__ ep2, int E) {
  int e = blockIdx.x * blockDim.x + threadIdx.x;
  if (e >= E) return;
  const float4* eav = reinterpret_cast<const float4*>(ea + (size_t)e * 16);
  float4 A = eav[0], B = eav[1], C = eav[2], D = eav[3];
  float ar[16] = {A.x, A.y, A.z, A.w, B.x, B.y, B.z, B.w,
                  C.x, C.y, C.z, C.w, D.x, D.y, D.z, D.w};
  int p = pos[e];
  float s0 = 0.f, s1 = 0.f;
  for (int d = 0; d < 64; ++d) {
    float p0 = dot16(WeT + d * 16, ar);
    float p1 = dot16(WeT + (64 + d) * 16, ar);
    s0 = fmaf(fmaxf(p0, 0.f), att0[128 + d], s0);
    s1 = fmaf(fmaxf(p1, 0.f), att1[128 + d], s1);
  }
  ep0[p] = s0;
  ep1[p] = s1;
  float4 s2v;
  float* s2 = (float*)&s2v;
#pragma unroll
  for (int h = 0; h < 4; ++h) {
    float s = 0.f;
    for (int d = 0; d < 64; ++d) {
      float pr = dot16(WeT + (128 + h * 64 + d) * 16, ar);
      s = fmaf(fmaxf(pr, 0.f), att2[h * 192 + 128 + d], s);
    }
    s2[h] = s;
  }
  reinterpret_cast<float4*>(ep2)[p] = s2v;
}

// ---------------- fused attention softmax + aggregate ----------------

template <int H>
__device__ __forceinline__ void loadH(const float* __restrict__ p, float* v) {
  if constexpr (H == 4) {
    float4 t = *reinterpret_cast<const float4*>(p);
    v[0] = t.x; v[1] = t.y; v[2] = t.z; v[3] = t.w;
  } else {
    v[0] = *p;
  }
}

// one wave per node, all H heads together.
// agg[n, h*F + f] = sum_e alpha_{e,h} * hin[src_e, f]
template <int F, int H>
__global__ __launch_bounds__(256) void k_attn_agg(
    const int* __restrict__ off, const int* __restrict__ ssrc,
    const float* __restrict__ hin, const float* __restrict__ ajd,
    const float* __restrict__ aid, const float* __restrict__ ep,
    float* __restrict__ outbuf, int N) {
  constexpr int FPL = F / 64;
  __shared__ float ls_alpha[4][64 * H];
  __shared__ int ls_src[4][64];
  const int wave = threadIdx.x >> 6, lane = threadIdx.x & 63;
  float* const la = ls_alpha[wave];
  int* const lsrc = ls_src[wave];

  for (int n = blockIdx.x * 4 + wave; n < N; n += gridDim.x * 4) {
    const int o0 = off[n];
    const int deg = off[n + 1] - o0;
    float aidn[H];
    loadH<H>(aid + (size_t)n * H, aidn);

    // ---- pass 1: online softmax stats (lane-parallel over edges) ----
    float m[H], s[H];
#pragma unroll
    for (int h = 0; h < H; ++h) { m[h] = -1e30f; s[h] = 0.f; }
    for (int i = lane; i < deg; i += 64) {
      int sr = ssrc[o0 + i];
      float aj[H], pv[H];
      loadH<H>(ajd + (size_t)sr * H, aj);
      loadH<H>(ep + (size_t)(o0 + i) * H, pv);
#pragma unroll
      for (int h = 0; h < H; ++h) {
        float sc = aj[h] + aidn[h] + pv[h];
        sc = sc > 0.f ? sc : 0.2f * sc;
        float mn = fmaxf(m[h], sc);
        s[h] = s[h] * __expf(m[h] - mn) + __expf(sc - mn);
        m[h] = mn;
      }
    }
#pragma unroll
    for (int o = 32; o > 0; o >>= 1) {
#pragma unroll
      for (int h = 0; h < H; ++h) {
        float m2 = __shfl_xor(m[h], o, 64);
        float s2 = __shfl_xor(s[h], o, 64);
        float mn = fmaxf(m[h], m2);
        s[h] = s[h] * __expf(m[h] - mn) + s2 * __expf(m2 - mn);
        m[h] = mn;
      }
    }
    float inv[H];
#pragma unroll
    for (int h = 0; h < H; ++h) inv[h] = 1.f / (s[h] + 1e-16f);

    // ---- pass 2: chunked alpha -> LDS, then 4-way unrolled gather+FMA ----
    float acc[H][FPL];
#pragma unroll
    for (int h = 0; h < H; ++h)
#pragma unroll
      for (int c = 0; c < FPL; ++c) acc[h][c] = 0.f;

    for (int base = 0; base < deg; base += 64) {
      const int cnt = min(64, deg - base);
      if (lane < cnt) {
        int i = base + lane;
        int sr = ssrc[o0 + i];
        lsrc[lane] = sr;
        float aj[H], pv[H];
        loadH<H>(ajd + (size_t)sr * H, aj);
        loadH<H>(ep + (size_t)(o0 + i) * H, pv);
#pragma unroll
        for (int h = 0; h < H; ++h) {
          float sc = aj[h] + aidn[h] + pv[h];
          sc = sc > 0.f ? sc : 0.2f * sc;
          la[lane * H + h] = __expf(sc - m[h]) * inv[h];
        }
      }
      asm volatile("s_waitcnt lgkmcnt(0)" ::: "memory");

      int j = 0;
      for (; j + 4 <= cnt; j += 4) {
        int srj[4];
        float av[4][H];
#pragma unroll
        for (int u = 0; u < 4; ++u) {
          srj[u] = lsrc[j + u];
          loadH<H>(la + (j + u) * H, av[u]);
        }
        float v[4][FPL];
#pragma unroll
        for (int u = 0; u < 4; ++u) {
          const float* hr = hin + (size_t)srj[u] * F + lane;
#pragma unroll
          for (int c = 0; c < FPL; ++c) v[u][c] = hr[c * 64];
        }
#pragma unroll
        for (int u = 0; u < 4; ++u)
#pragma unroll
          for (int h = 0; h < H; ++h)
#pragma unroll
            for (int c = 0; c < FPL; ++c)
              acc[h][c] = fmaf(av[u][h], v[u][c], acc[h][c]);
      }
      for (; j < cnt; ++j) {
        int sr = lsrc[j];
        float av[H];
        loadH<H>(la + j * H, av);
        const float* hr = hin + (size_t)sr * F + lane;
#pragma unroll
        for (int h = 0; h < H; ++h)
#pragma unroll
          for (int c = 0; c < FPL; ++c)
            acc[h][c] = fmaf(av[h], hr[c * 64], acc[h][c]);
      }
    }

    float* ob = outbuf + (size_t)n * (H * F);
#pragma unroll
    for (int h = 0; h < H; ++h)
#pragma unroll
      for (int c = 0; c < FPL; ++c) ob[h * F + c * 64 + lane] = acc[h][c];
  }
}

// ---------------- post GEMM: out[n, h*64+j] = agg[n,h,:] @ W[:, h*64+j] (+ELU) ----------------

template <int F, int H, bool ELU_ACT>
__global__ __launch_bounds__(256) void k_post(const float* __restrict__ agg, const float* __restrict__ W,
                       float* __restrict__ out, int N) {
  constexpr int CO = H * 64;
  __shared__ float Wl[F * CO];
  for (int i = threadIdx.x; i < F * CO; i += 256) Wl[i] = W[i];
  __syncthreads();
  constexpr int GPB = 256 / CO;
  int g = threadIdx.x / CO;
  int j = threadIdx.x % CO;
  int h = j >> 6;
  for (int n = blockIdx.x * GPB + g; n < N; n += gridDim.x * GPB) {
    const float* ag = agg + (size_t)n * (H * F) + (size_t)h * F;
    float a = 0.f;
#pragma unroll 8
    for (int k = 0; k < F; ++k) a = fmaf(ag[k], Wl[k * CO + j], a);
    if (ELU_ACT) a = (a > 0.f) ? a : expm1f(a);
    out[(size_t)n * CO + j] = a;
  }
}

// ---------------- launch ----------------

extern "C" void kernel_launch(void* const* d_in, const int* in_sizes, int n_in,
                              void* d_out, int out_size, void* d_ws, size_t ws_size,
                              hipStream_t stream) {
  const float* x    = (const float*)d_in[0];
  const int*   ei   = (const int*)d_in[1];
  const float* ea   = (const float*)d_in[2];
  const float* W0   = (const float*)d_in[3];
  const float* We0  = (const float*)d_in[4];
  const float* att0 = (const float*)d_in[5];
  const float* W1   = (const float*)d_in[6];
  const float* We1  = (const float*)d_in[7];
  const float* att1 = (const float*)d_in[8];
  const float* W2   = (const float*)d_in[9];
  const float* We2  = (const float*)d_in[10];
  const float* att2 = (const float*)d_in[11];
  float* out = (float*)d_out;

  const int N = in_sizes[0] / 128;   // 50000
  const int E = in_sizes[2] / 16;    // 800000

  char* p = (char*)d_ws;
  auto alloc = [&](size_t bytes) {
    char* r = p;
    p += (bytes + 255) & ~(size_t)255;
    return r;
  };
  int*   flag = (int*)  alloc(sizeof(int));
  int*   off  = (int*)  alloc((size_t)(N + 1) * sizeof(int));
  int*   cur  = (int*)  alloc((size_t)N * sizeof(int));
  int*   pos  = (int*)  alloc((size_t)E * sizeof(int));
  int*   ssrc = (int*)  alloc((size_t)E * sizeof(int));
  float* WeT  = (float*)alloc(384 * 16 * sizeof(float));
  float* waj0 = (float*)alloc(128 * sizeof(float));
  float* wai0 = (float*)alloc(128 * sizeof(float));
  float* waj1 = (float*)alloc(64 * sizeof(float));
  float* wai1 = (float*)alloc(64 * sizeof(float));
  float* waj2 = (float*)alloc(256 * sizeof(float));
  float* wai2 = (float*)alloc(256 * sizeof(float));
  float* ajd  = (float*)alloc((size_t)N * 4 * sizeof(float));
  float* aid  = (float*)alloc((size_t)N * 4 * sizeof(float));
  float* ep0  = (float*)alloc((size_t)E * sizeof(float));
  float* ep1  = (float*)alloc((size_t)E * sizeof(float));
  float* ep2  = (float*)alloc((size_t)E * 4 * sizeof(float));
  float* hbuf = (float*)alloc((size_t)N * 64 * sizeof(float));
  float* agg  = (float*)alloc((size_t)N * 256 * sizeof(float));

  const int eb = (E + THR - 1) / THR;
  const int nb = (N + THR - 1) / THR;
  const int ab = (N + 3) / 4;

  hipMemsetAsync(flag, 0, sizeof(int), stream);
  hipMemsetAsync(cur, 0, (size_t)N * sizeof(int), stream);

  k_detect<<<16, THR, 0, stream>>>(ei, flag);
  k_count<<<eb, THR, 0, stream>>>(ei, flag, cur, E);
  k_scan<<<1, 1024, 0, stream>>>(cur, off, N);
  k_scatter<<<eb, THR, 0, stream>>>(ei, flag, cur, pos, ssrc, E);

  k_transpose_we<<<24, THR, 0, stream>>>(We0, We1, We2, WeT);
  k_fold_att<<<1, 128, 0, stream>>>(W0, att0, waj0, wai0, 128, 1);
  k_fold_att<<<1, 64, 0, stream>>>(W1, att1, waj1, wai1, 64, 1);
  k_fold_att<<<1, 256, 0, stream>>>(W2, att2, waj2, wai2, 64, 4);
  k_ep<<<eb, THR, 0, stream>>>(ea, WeT, att0, att1, att2, pos, ep0, ep1, ep2, E);

  // layer 0: Cin=128, H=1
  k_node_dots<128, 1><<<nb, THR, 0, stream>>>(x, waj0, wai0, ajd, aid, N);
  k_attn_agg<128, 1><<<ab, THR, 0, stream>>>(off, ssrc, x, ajd, aid, ep0, agg, N);
  k_post<128, 1, true><<<1024, THR, 0, stream>>>(agg, W0, hbuf, N);

  // layer 1: Cin=64, H=1
  k_node_dots<64, 1><<<nb, THR, 0, stream>>>(hbuf, waj1, wai1, ajd, aid, N);
  k_attn_agg<64, 1><<<ab, THR, 0, stream>>>(off, ssrc, hbuf, ajd, aid, ep1, agg, N);
  k_post<64, 1, true><<<1024, THR, 0, stream>>>(agg, W1, hbuf, N);

  // layer 2: Cin=64, H=4 (all heads in one wave)
  k_node_dots<64, 4><<<nb, THR, 0, stream>>>(hbuf, waj2, wai2, ajd, aid, N);
  k_attn_agg<64, 4><<<ab, THR, 0, stream>>>(off, ssrc, hbuf, ajd, aid, ep2, agg, N);
  k_post<64, 4, false><<<1024, THR, 0, stream>>>(agg, W2, out, N);
}